// Round 9
// baseline (553.332 us; speedup 1.0000x reference)
//
#include <hip/hip_runtime.h>
#include <type_traits>

#define NNODES 98304
#define NB 4
#define NX 128
#define FACE (NX * NX)   // 16384 nodes per cubed-sphere face

typedef __attribute__((ext_vector_type(8))) short short8;
typedef __attribute__((ext_vector_type(8))) unsigned short ushort8;
typedef __attribute__((ext_vector_type(4))) float f32x4;

__device__ __forceinline__ float bf2f(unsigned short u) {
  union { unsigned int u; float f; } c; c.u = ((unsigned int)u) << 16; return c.f;
}
__device__ __forceinline__ float asf(unsigned int u) {
  union { unsigned int u; float f; } c; c.u = u; return c.f;
}
__device__ __forceinline__ unsigned short f2bf(float f) {
  union { float f; unsigned int u; } c; c.f = f;
  unsigned int r = 0x7FFFu + ((c.u >> 16) & 1u);
  return (unsigned short)((c.u + r) >> 16);
}
// packed f32x2 -> bf16x2 (RNE); low16 = lo
__device__ __forceinline__ unsigned int cvtpk(float lo, float hi) {
  unsigned int r;
  asm("v_cvt_pk_bf16_f32 %0, %1, %2" : "=v"(r) : "v"(lo), "v"(hi));
  return r;
}

// mean of 4 bf16x8 rows (LDS pointers), f32 accumulate, repack bf16.
// bf16 hi element of a dword is already f32 bits (& 0xFFFF0000); lo is <<16.
__device__ __forceinline__ short8 mean4(const unsigned short* pA, const unsigned short* pB,
                                        const unsigned short* pC, const unsigned short* pD) {
  uint4 a = *(const uint4*)pA, b = *(const uint4*)pB, c = *(const uint4*)pC, d = *(const uint4*)pD;
  const unsigned* pa = &a.x; const unsigned* pb = &b.x;
  const unsigned* pc = &c.x; const unsigned* pd = &d.x;
  union { uint4 u; short8 s; } o;
  unsigned* po = &o.u.x;
  #pragma unroll
  for (int i = 0; i < 4; ++i) {
    float lo = (asf(pa[i] << 16) + asf(pb[i] << 16)) + (asf(pc[i] << 16) + asf(pd[i] << 16));
    float hi = (asf(pa[i] & 0xFFFF0000u) + asf(pb[i] & 0xFFFF0000u)) +
               (asf(pc[i] & 0xFFFF0000u) + asf(pd[i] & 0xFFFF0000u));
    po[i] = cvtpk(lo * 0.25f, hi * 0.25f);
  }
  return o.s;
}

// ---- pre-transposed bf16 weight tables: WT[col][k], k-order [Ws; Wn] ----
__device__ __attribute__((aligned(16))) unsigned short g_wt[59392];
#define WT_A12 0        // W1: [128][128]
#define WT_B12 16384    // W2: [64][256]
#define WT_45  32768    // W4: [32][64] (used for both fused stages)
#define WT_A67 34816    // W5: [64][128]
#define WT_B67 43008    // W6: [64][256]

__global__ void prep_wt(const float* __restrict__ Ws, const float* __restrict__ Wn,
                        int FIN, int FOUT, int dstoff) {
  const int K = 2 * FIN, total = FOUT * K;
  for (int e = blockIdx.x * 256 + threadIdx.x; e < total; e += gridDim.x * 256) {
    const int col = e / K, k = e % K;
    const float v = (k < FIN) ? Ws[(size_t)k * FOUT + col] : Wn[(size_t)(k - FIN) * FOUT + col];
    g_wt[dstoff + e] = f2bf(v);   // e == col*K + k
  }
}

// ============ fused two-layer SAGE kernel (halo tiles) ============
// Per block: one batch b, one 8x8 node tile. Stage A computes
// hA = relu([X|mean(X)] @ WTa + ba) on the halo-1 box (10x10) into LDS;
// stage B computes [hA (|ext) | mean(hA) (| mean(ext))] @ WTb + bb on the tile.
// Torus wrap handled at staging; interior math is slot-space.
template<int FA, int FOA, int FEXT, int FOB, int SRCK, int DSTK, bool RELUB, int MINW>
__global__ __launch_bounds__(256, MINW)
void sage_fused2(const void* __restrict__ srcA, int ssA, int soA,
                 const unsigned short* __restrict__ srcE, int ssE, int soE,
                 void* __restrict__ dst, int dstr, int dof,
                 int wtaOff, int wtbOff,
                 const float* __restrict__ ba, const float* __restrict__ bb)
{
  constexpr int TI = 8, TJ = 8;
  constexpr int RAJ = TJ + 4, NRA = (TI + 4) * RAJ;  // 12, 144 (halo-2 box)
  constexpr int HJ = TJ + 2, NH = (TI + 2) * HJ;     // 10, 100 (halo-1 box)
  constexpr int MA = 112;                            // 7 row-frags (pad of 100)
  constexpr int KA = 2 * FA, KB = 2 * (FOA + FEXT);
  constexpr int CFA = FOA / 16, CFB = FOB / 16;
  constexpr int LDA = FA + 8, LDH = FOA + 8, LDE = FEXT + 8;

  __shared__ unsigned short rawA[NRA][LDA];
  __shared__ unsigned short H[MA][LDH];
  __shared__ unsigned short rawE[FEXT ? NH : 1][FEXT ? LDE : 1];

  const int tid = threadIdx.x;
  const int b = blockIdx.x & 3;
  const int tt = blockIdx.x >> 2;
  const int t = tt >> 8;
  const int i0 = ((tt >> 4) & 15) * TI, j0 = (tt & 15) * TJ;
  const int nbase = t * FACE;

  // ---- stage raw A-input (halo-2 box) into LDS as bf16 ----
  constexpr int CHA = FA / 8;
  for (int u = tid; u < NRA * CHA; u += 256) {
    const int s = u / CHA, c = (u - s * CHA) * 8;
    const int di = s / RAJ - 2, dj = s % RAJ - 2;
    const int n = nbase + ((i0 + di) & (NX - 1)) * NX + ((j0 + dj) & (NX - 1));
    uint4 v;
    if constexpr (SRCK == 0) {
      const float* p = (const float*)srcA + ((size_t)b * NNODES + n) * FA + c;
      const float4 a = *(const float4*)p, q = *(const float4*)(p + 4);
      v = make_uint4(cvtpk(a.x, a.y), cvtpk(a.z, a.w), cvtpk(q.x, q.y), cvtpk(q.z, q.w));
    } else {
      v = *(const uint4*)((const unsigned short*)srcA + ((size_t)n * NB + b) * ssA + soA + c);
    }
    *(uint4*)&rawA[s][c] = v;
  }
  if constexpr (FEXT != 0) {
    constexpr int CHE = FEXT / 8;
    for (int u = tid; u < NH * CHE; u += 256) {
      const int s = u / CHE, c = (u - s * CHE) * 8;
      const int di = s / HJ - 1, dj = s % HJ - 1;
      const int n = nbase + ((i0 + di) & (NX - 1)) * NX + ((j0 + dj) & (NX - 1));
      *(uint4*)&rawE[s][c] =
          *(const uint4*)(srcE + ((size_t)n * NB + b) * ssE + soE + c);
    }
  }
  __syncthreads();

  const int lane = tid & 63, wave = tid >> 6;
  const int fn = lane & 15, fg = lane >> 4;

  // ---- stage A: swapped MFMA (A=weights) so lane holds 4 consecutive fouts
  //      of one row -> 8B ds_write into H. Waves: frags {w, w+4 (<7)}. ----
  {
    const unsigned short* wt = g_wt + wtaOff;
    #pragma unroll 1
    for (int rfi = 0; rfi < 2; ++rfi) {
      const int rf = wave + rfi * 4;
      if (rf >= 7) break;
      const int r = rf * 16 + fn;                    // H row this lane covers
      const int rc = r < NH ? r : NH - 1;            // clamp pad rows (unused)
      const int sA = (rc / HJ + 1) * RAJ + (rc % HJ) + 1;
      f32x4 acc[CFA];
      #pragma unroll
      for (int cf = 0; cf < CFA; ++cf) {
        const float4 bt = *(const float4*)(ba + cf * 16 + fg * 4);
        acc[cf] = (f32x4){bt.x, bt.y, bt.z, bt.w};
      }
      #pragma unroll 1
      for (int ks = 0; ks < KA / 32; ++ks) {
        short8 xf;
        if (ks < FA / 32) {
          xf = *(const short8*)&rawA[sA][ks * 32 + fg * 8];
        } else {
          const int cc = (ks - FA / 32) * 32 + fg * 8;
          xf = mean4(&rawA[sA - RAJ][cc], &rawA[sA + RAJ][cc],
                     &rawA[sA - 1][cc], &rawA[sA + 1][cc]);
        }
        #pragma unroll
        for (int cf = 0; cf < CFA; ++cf) {
          const short8 wf = *(const short8*)(wt + (size_t)(cf * 16 + fn) * KA + ks * 32 + fg * 8);
          acc[cf] = __builtin_amdgcn_mfma_f32_16x16x32_bf16(wf, xf, acc[cf], 0, 0, 0);
        }
      }
      #pragma unroll
      for (int cf = 0; cf < CFA; ++cf) {
        const uint2 u = make_uint2(
            cvtpk(fmaxf(acc[cf][0], 0.f), fmaxf(acc[cf][1], 0.f)),
            cvtpk(fmaxf(acc[cf][2], 0.f), fmaxf(acc[cf][3], 0.f)));
        *(uint2*)&H[r][cf * 16 + fg * 4] = u;
      }
    }
  }
  __syncthreads();

  // ---- stage B: unswapped MFMA (proven clean global-store pattern) ----
  {
    const unsigned short* wt = g_wt + wtbOff;
    const int r = wave * 16 + fn;                    // tile row 0..63
    const int sH = (r / TJ + 1) * HJ + (r % TJ) + 1; // halo-1 slot
    f32x4 acc[CFB];
    #pragma unroll
    for (int cf = 0; cf < CFB; ++cf) {
      const float bt = bb[cf * 16 + fn];
      acc[cf] = (f32x4){bt, bt, bt, bt};
    }
    constexpr int S1 = FOA / 32;          // self-H ksteps
    constexpr int S2 = S1 + FEXT / 32;    // + self-E
    constexpr int S3 = S2 + FOA / 32;     // + mean-H
    #pragma unroll 1
    for (int ks = 0; ks < KB / 32; ++ks) {
      short8 xf;
      if constexpr (FEXT == 0) {
        if (ks < S1) {
          xf = *(const short8*)&H[sH][ks * 32 + fg * 8];
        } else {
          const int cc = (ks - S1) * 32 + fg * 8;
          xf = mean4(&H[sH - HJ][cc], &H[sH + HJ][cc], &H[sH - 1][cc], &H[sH + 1][cc]);
        }
      } else {
        if (ks < S1) {
          xf = *(const short8*)&H[sH][ks * 32 + fg * 8];
        } else if (ks < S2) {
          xf = *(const short8*)&rawE[sH][(ks - S1) * 32 + fg * 8];
        } else if (ks < S3) {
          const int cc = (ks - S2) * 32 + fg * 8;
          xf = mean4(&H[sH - HJ][cc], &H[sH + HJ][cc], &H[sH - 1][cc], &H[sH + 1][cc]);
        } else {
          const int cc = (ks - S3) * 32 + fg * 8;
          xf = mean4(&rawE[sH - HJ][cc], &rawE[sH + HJ][cc], &rawE[sH - 1][cc], &rawE[sH + 1][cc]);
        }
      }
      #pragma unroll
      for (int cf = 0; cf < CFB; ++cf) {
        const short8 wf = *(const short8*)(wt + (size_t)(cf * 16 + fn) * KB + ks * 32 + fg * 8);
        acc[cf] = __builtin_amdgcn_mfma_f32_16x16x32_bf16(xf, wf, acc[cf], 0, 0, 0);
      }
    }
    // store: D row = wave*16 + fg*4 + j (tile node), col = cf*16 + fn
    #pragma unroll
    for (int cf = 0; cf < CFB; ++cf) {
      const int col = cf * 16 + fn;
      #pragma unroll
      for (int j = 0; j < 4; ++j) {
        const int rr = wave * 16 + fg * 4 + j;
        const int n = nbase + (i0 + (rr / TJ)) * NX + j0 + (rr % TJ);
        float v = acc[cf][j];
        if (RELUB) v = fmaxf(v, 0.f);
        if constexpr (DSTK == 0)
          ((float*)dst)[((size_t)b * NNODES + n) * FOB + col] = v;
        else
          ((unsigned short*)dst)[((size_t)n * NB + b) * dstr + dof + col] = f2bf(v);
      }
    }
  }
}

// ============ round-8 single-layer kernel (kept for L3) ============
__device__ __forceinline__ void tile_barrier() {
  asm volatile("s_waitcnt lgkmcnt(0)" ::: "memory");
  __builtin_amdgcn_s_barrier();
  asm volatile("" ::: "memory");
}
constexpr int rows_for(int FIN)            { return FIN == 32 ? 64 : 32; }
constexpr int grid_for(int FIN, int SRCK)  { return (FIN == 128 || SRCK == 0) ? 1024 : 1536; }
constexpr int minw_for(int FIN, int SRCK)  { return (FIN == 128 || SRCK == 0) ? 4 : 6; }

template<int FIN, int FOUT, int SRCK, int DSTK, bool RELU>
__global__ __launch_bounds__(256, minw_for(FIN, SRCK))
void sage_mfma(const void* __restrict__ srcp, int sstride, int soff,
               void* __restrict__ dstp, int dstride, int doff,
               const float* __restrict__ Ws, const float* __restrict__ Wn,
               const float* __restrict__ bias, const int* __restrict__ nbr)
{
  constexpr int ROWS = rows_for(FIN);
  constexpr int GRID = grid_for(FIN, SRCK);
  constexpr int NPT = ROWS / 4;
  constexpr int NTILES = (NNODES * NB) / ROWS;
  constexpr int K = 2 * FIN;
  constexpr int KSTEPS = K / 32;
  constexpr int LD = K + 8;
  constexpr int WAVES_N = (FOUT >= 64) ? 4 : 2;
  constexpr int WAVES_M = 4 / WAVES_N;
  constexpr int CF = FOUT / (16 * WAVES_N);
  constexpr int RF = ROWS / (16 * WAVES_M);
  constexpr int CHUNKS = FIN / 8;
  constexpr int ITERS = (ROWS * CHUNKS) / 256;
  constexpr int PF = ITERS;

  __shared__ unsigned short As[2][ROWS][LD];

  const int tid = threadIdx.x;
  const int wave = tid >> 6, lane = tid & 63;
  const int wn = wave % WAVES_N, wm = wave / WAVES_N;
  const int colbase = wn * (FOUT / WAVES_N);
  const int rowbase = wm * (ROWS / WAVES_M);
  const int fn = lane & 15, fg = lane >> 4;

  short8 Bfrag[KSTEPS][CF];
  float bv[CF];
  #pragma unroll
  for (int ks = 0; ks < KSTEPS; ++ks) {
    const float* wb = (ks * 32 < FIN) ? (Ws + (size_t)(ks * 32) * FOUT)
                                      : (Wn + (size_t)(ks * 32 - FIN) * FOUT);
    #pragma unroll
    for (int cf = 0; cf < CF; ++cf) {
      const int col = colbase + cf * 16 + fn;
      short8 f;
      #pragma unroll
      for (int j = 0; j < 8; ++j)
        f[j] = (short)f2bf(wb[(size_t)(fg * 8 + j) * FOUT + col]);
      Bfrag[ks][cf] = f;
    }
  }
  #pragma unroll
  for (int cf = 0; cf < CF; ++cf) bv[cf] = bias[colbase + cf * 16 + fn];

  struct G1 { ushort8 s, n0, n1, n2, n3; };
  using PG = G1;

  auto issue = [&](int node0, int it, PG& p) {
    const int g = tid + it * 256;
    const int r = g / CHUNKS;
    const int c = (g - r * CHUNKS) * 8;
    const int n = node0 + (r >> 2);
    const int b = r & 3;
    const int4 nb4 = reinterpret_cast<const int4*>(nbr)[n];
    const unsigned short* s = (const unsigned short*)srcp;
    auto ld = [&](int nn) {
      return *reinterpret_cast<const ushort8*>(s + ((size_t)nn * NB + b) * sstride + soff + c);
    };
    p.s = ld(n); p.n0 = ld(nb4.x); p.n1 = ld(nb4.y); p.n2 = ld(nb4.z); p.n3 = ld(nb4.w);
  };
  auto finish = [&](int buf, int it, PG& p) {
    const int g = tid + it * 256;
    const int r = g / CHUNKS;
    const int c = (g - r * CHUNKS) * 8;
    uint4 xv = make_uint4(
        (unsigned)(unsigned short)p.s[0] | ((unsigned)(unsigned short)p.s[1] << 16),
        (unsigned)(unsigned short)p.s[2] | ((unsigned)(unsigned short)p.s[3] << 16),
        (unsigned)(unsigned short)p.s[4] | ((unsigned)(unsigned short)p.s[5] << 16),
        (unsigned)(unsigned short)p.s[6] | ((unsigned)(unsigned short)p.s[7] << 16));
    float sum[8];
    #pragma unroll
    for (int j = 0; j < 8; ++j)
      sum[j] = (bf2f(p.n0[j]) + bf2f(p.n1[j])) + (bf2f(p.n2[j]) + bf2f(p.n3[j]));
    uint4 mv = make_uint4(cvtpk(sum[0] * 0.25f, sum[1] * 0.25f), cvtpk(sum[2] * 0.25f, sum[3] * 0.25f),
                          cvtpk(sum[4] * 0.25f, sum[5] * 0.25f), cvtpk(sum[6] * 0.25f, sum[7] * 0.25f));
    *reinterpret_cast<uint4*>(&As[buf][r][c]) = xv;
    *reinterpret_cast<uint4*>(&As[buf][r][FIN + c]) = mv;
  };

  {
    PG p[ITERS];
    #pragma unroll
    for (int it = 0; it < ITERS; ++it) issue(blockIdx.x * NPT, it, p[it]);
    #pragma unroll
    for (int it = 0; it < ITERS; ++it) finish(0, it, p[it]);
  }

  int cur = 0;
  for (int tile = blockIdx.x; tile < NTILES; tile += GRID) {
    const int node0 = tile * NPT;
    const bool hasnext = (tile + GRID) < NTILES;
    const int nnode0 = (tile + GRID) * NPT;

    PG ptop[PF];
    if (hasnext) {
      #pragma unroll
      for (int it = 0; it < PF; ++it) issue(nnode0, it, ptop[it]);
    }

    tile_barrier();

    f32x4 acc[RF][CF];
    #pragma unroll
    for (int rf = 0; rf < RF; ++rf)
      #pragma unroll
      for (int cf = 0; cf < CF; ++cf)
        acc[rf][cf] = (f32x4){bv[cf], bv[cf], bv[cf], bv[cf]};

    #pragma unroll
    for (int ks = 0; ks < KSTEPS; ++ks) {
      short8 a[RF];
      #pragma unroll
      for (int rf = 0; rf < RF; ++rf)
        a[rf] = *reinterpret_cast<const short8*>(&As[cur][rowbase + rf * 16 + fn][ks * 32 + fg * 8]);
      #pragma unroll
      for (int rf = 0; rf < RF; ++rf)
        #pragma unroll
        for (int cf = 0; cf < CF; ++cf)
          acc[rf][cf] = __builtin_amdgcn_mfma_f32_16x16x32_bf16(
              a[rf], Bfrag[ks][cf], acc[rf][cf], 0, 0, 0);
    }

    #pragma unroll
    for (int rf = 0; rf < RF; ++rf) {
      #pragma unroll
      for (int cf = 0; cf < CF; ++cf) {
        const int col = colbase + cf * 16 + fn;
        #pragma unroll
        for (int j = 0; j < 4; ++j) {
          const int row = rowbase + rf * 16 + fg * 4 + j;
          const int n = node0 + (row >> 2);
          const int b = row & 3;
          float v = acc[rf][cf][j];
          if (RELU) v = fmaxf(v, 0.f);
          if (DSTK == 0)
            ((float*)dstp)[((size_t)b * NNODES + n) * FOUT + col] = v;
          else
            ((unsigned short*)dstp)[((size_t)n * NB + b) * dstride + doff + col] = f2bf(v);
        }
      }
    }

    if (hasnext) {
      #pragma unroll
      for (int it = 0; it < PF; ++it) finish(cur ^ 1, it, ptop[it]);
    }
    cur ^= 1;
  }
}

extern "C" void kernel_launch(void* const* d_in, const int* in_sizes, int n_in,
                              void* d_out, int out_size, void* d_ws, size_t ws_size,
                              hipStream_t stream) {
  const float* x  = (const float*)d_in[0];   // [B, N, 64] fp32
  const int* nbr  = (const int*)d_in[1];     // [N, 4] int32
  const float* W1s = (const float*)d_in[2],  *W1n = (const float*)d_in[3],  *b1 = (const float*)d_in[4];
  const float* W2s = (const float*)d_in[5],  *W2n = (const float*)d_in[6],  *b2 = (const float*)d_in[7];
  const float* W3s = (const float*)d_in[8],  *W3n = (const float*)d_in[9],  *b3 = (const float*)d_in[10];
  const float* W4s = (const float*)d_in[11], *W4n = (const float*)d_in[12], *b4 = (const float*)d_in[13];
  const float* W5s = (const float*)d_in[14], *W5n = (const float*)d_in[15], *b5 = (const float*)d_in[16];
  const float* W6s = (const float*)d_in[17], *W6n = (const float*)d_in[18], *b6 = (const float*)d_in[19];

  // Single d_ws buffer [N, 4, 128] bf16: cols 0:32 = h5a, 32:64 = h3, 64:128 = h2.
  // h1, h4, h6a are never materialized (fused). d_out is pure output.
  unsigned short* hbuf = (unsigned short*)d_ws;

  const dim3 blk(256);

  // weight transpose prep (bf16 [FOUT][K], k-order [Ws;Wn]) — tiny
  prep_wt<<<dim3(32), blk, 0, stream>>>(W1s, W1n, 64, 128, WT_A12);
  prep_wt<<<dim3(32), blk, 0, stream>>>(W2s, W2n, 128, 64, WT_B12);
  prep_wt<<<dim3(8),  blk, 0, stream>>>(W4s, W4n, 32, 32, WT_45);
  prep_wt<<<dim3(16), blk, 0, stream>>>(W5s, W5n, 64, 64, WT_A67);
  prep_wt<<<dim3(32), blk, 0, stream>>>(W6s, W6n, 128, 64, WT_B67);

  // L1+L2 fused: x (fp32) -> h2 (cols 64:128)
  sage_fused2<64, 128, 0, 64, 0, 1, true, 3><<<dim3(6144), blk, 0, stream>>>(
      x, 0, 0, nullptr, 0, 0, hbuf, 128, 64, WT_A12, WT_B12, b1, b2);
  // L3 (unfused): h2 -> h3 (cols 32:64)
  sage_mfma<64, 32, 1, 1, true><<<dim3(grid_for(64, 1)), blk, 0, stream>>>(
      hbuf, 128, 64, hbuf, 128, 32, W3s, W3n, b3, nbr);
  // L4+L5 fused (shared W4): h3 -> h5a (cols 0:32)
  sage_fused2<32, 32, 0, 32, 1, 1, true, 4><<<dim3(6144), blk, 0, stream>>>(
      hbuf, 128, 32, nullptr, 0, 0, hbuf, 128, 0, WT_45, WT_45, b4, b4);
  // L6+L7 fused: [h5a|h3] (cols 0:64) + ext h2 (cols 64:128) -> out fp32
  sage_fused2<64, 64, 64, 64, 1, 0, false, 3><<<dim3(6144), blk, 0, stream>>>(
      hbuf, 128, 0, hbuf, 128, 64, d_out, 0, 0, WT_A67, WT_B67, b5, b6);
}

// Round 10
// 313.445 us; speedup vs baseline: 1.7653x; 1.7653x over previous
//
#include <hip/hip_runtime.h>
#include <type_traits>

#define NNODES 98304
#define NB 4
#define NX 128
#define FACE (NX * NX)

typedef __attribute__((ext_vector_type(8))) short short8;
typedef __attribute__((ext_vector_type(8))) unsigned short ushort8;
typedef __attribute__((ext_vector_type(4))) float f32x4;

__device__ __forceinline__ float bf2f(unsigned short u) {
  union { unsigned int u; float f; } c; c.u = ((unsigned int)u) << 16; return c.f;
}
__device__ __forceinline__ float asf(unsigned int u) {
  union { unsigned int u; float f; } c; c.u = u; return c.f;
}
__device__ __forceinline__ unsigned short f2bf(float f) {
  union { float f; unsigned int u; } c; c.f = f;
  unsigned int r = 0x7FFFu + ((c.u >> 16) & 1u);
  return (unsigned short)((c.u + r) >> 16);
}
__device__ __forceinline__ unsigned int cvtpk(float lo, float hi) {
  unsigned int r;
  asm("v_cvt_pk_bf16_f32 %0, %1, %2" : "=v"(r) : "v"(lo), "v"(hi));
  return r;
}

// mean of 4 bf16x8 rows (16B-aligned LDS pointers), f32 accumulate, repack.
__device__ __forceinline__ short8 mean4(const unsigned short* pA, const unsigned short* pB,
                                        const unsigned short* pC, const unsigned short* pD) {
  uint4 a = *(const uint4*)pA, b = *(const uint4*)pB, c = *(const uint4*)pC, d = *(const uint4*)pD;
  const unsigned* pa = &a.x; const unsigned* pb = &b.x;
  const unsigned* pc = &c.x; const unsigned* pd = &d.x;
  union { uint4 u; short8 s; } o;
  unsigned* po = &o.u.x;
  #pragma unroll
  for (int i = 0; i < 4; ++i) {
    float lo = (asf(pa[i] << 16) + asf(pb[i] << 16)) + (asf(pc[i] << 16) + asf(pd[i] << 16));
    float hi = (asf(pa[i] & 0xFFFF0000u) + asf(pb[i] & 0xFFFF0000u)) +
               (asf(pc[i] & 0xFFFF0000u) + asf(pd[i] & 0xFFFF0000u));
    po[i] = cvtpk(lo * 0.25f, hi * 0.25f);
  }
  return o.s;
}

// ---- pre-transposed bf16 weight tables: WT[col][k], k-order [Ws; Wn] ----
__device__ __attribute__((aligned(16))) unsigned short g_wt[59392];
#define WT_A12 0        // W1: [128][128]
#define WT_B12 16384    // W2: [64][256]
#define WT_45  32768    // W4: [32][64]
#define WT_A67 34816    // W5: [64][128]
#define WT_B67 43008    // W6: [64][256]

__global__ void prep_wt(const float* __restrict__ Ws, const float* __restrict__ Wn,
                        int FIN, int FOUT, int dstoff) {
  const int K = 2 * FIN, total = FOUT * K;
  for (int e = blockIdx.x * 256 + threadIdx.x; e < total; e += gridDim.x * 256) {
    const int col = e / K, k = e % K;
    const float v = (k < FIN) ? Ws[(size_t)k * FOUT + col] : Wn[(size_t)(k - FIN) * FOUT + col];
    g_wt[dstoff + e] = f2bf(v);
  }
}

// ============ fused two-layer SAGE kernel v2 ============
// Per block: one batch b, one 8x8 node tile. Phases:
//  1 stage rawA (halo-2) [+rawE halo-1]  2 meanA precompute
//  3 stage A (reg-weights, pure ds_read K-loop) -> H (halo-1)
//  4 meanH [+meanE] into union region (rawA/meanA dead)
//  5 stage B -> global.  All K-loops fully unrolled, weights in VGPRs.
template<int FA, int FOA, int FEXT, int FOB, int SRCK, int DSTK, bool RELUB, int MINW>
__global__ __launch_bounds__(256, MINW)
void sage_fused2(const void* __restrict__ srcA, int ssA, int soA,
                 const unsigned short* __restrict__ srcE, int ssE, int soE,
                 void* __restrict__ dst, int dstr, int dof,
                 int wtaOff, int wtbOff,
                 const float* __restrict__ ba, const float* __restrict__ bb)
{
  constexpr int TI = 8, TJ = 8;
  constexpr int RAJ = TJ + 4, NRA = (TI + 4) * RAJ;   // 12, 144 (halo-2 box)
  constexpr int HJ = TJ + 2, NH = (TI + 2) * HJ;      // 10, 100 (halo-1 box)
  constexpr int MA = 112;                             // 7 row-frags
  constexpr int KA = 2 * FA, KSA = KA / 32;
  constexpr int KB = 2 * (FOA + FEXT), KSB = KB / 32;
  constexpr int CFA = FOA / 16, CFB = FOB / 16;
  constexpr int LDA = FA + 8, LDH = FOA + 8;
  constexpr int LDE = FEXT ? FEXT + 8 : 8;
  // wave -> (col-slice, row-group) split so weights fit in registers
  constexpr int NCWA = (CFA >= 4) ? 4 : CFA;  constexpr int CFWA = CFA / NCWA;
  constexpr int RWGA = 4 / NCWA;
  constexpr int NCWB = (CFB >= 4) ? 4 : CFB;  constexpr int RWGB = 4 / NCWB;

  struct ShA { unsigned short rawA[NRA][LDA]; unsigned short meanA[NH][LDA]; };
  struct ShB { unsigned short meanH[64][LDH]; unsigned short meanE[FEXT ? 64 : 1][LDE]; };
  union ShU { ShA a; ShB b; };
  __shared__ ShU sh;
  __shared__ unsigned short H[MA][LDH];
  __shared__ unsigned short rawE[FEXT ? NH : 1][LDE];

  const int tid = threadIdx.x;
  const int b = blockIdx.x & 3;
  const int tt = blockIdx.x >> 2;
  const int t = tt >> 8;
  const int i0 = ((tt >> 4) & 15) * TI, j0 = (tt & 15) * TJ;
  const int nbase = t * FACE;

  // ---- phase 1: stage rawA (halo-2) [+ rawE (halo-1)] ----
  constexpr int CHA = FA / 8;
  for (int e = tid; e < NRA * CHA; e += 256) {
    const int s = e / CHA, c = (e - s * CHA) * 8;
    const int di = s / RAJ - 2, dj = s % RAJ - 2;
    const int n = nbase + ((i0 + di) & (NX - 1)) * NX + ((j0 + dj) & (NX - 1));
    uint4 v;
    if constexpr (SRCK == 0) {
      const float* p = (const float*)srcA + ((size_t)b * NNODES + n) * FA + c;
      const float4 a = *(const float4*)p, q = *(const float4*)(p + 4);
      v = make_uint4(cvtpk(a.x, a.y), cvtpk(a.z, a.w), cvtpk(q.x, q.y), cvtpk(q.z, q.w));
    } else {
      v = *(const uint4*)((const unsigned short*)srcA + ((size_t)n * NB + b) * ssA + soA + c);
    }
    *(uint4*)&sh.a.rawA[s][c] = v;
  }
  if constexpr (FEXT != 0) {
    constexpr int CHE = FEXT / 8;
    for (int e = tid; e < NH * CHE; e += 256) {
      const int s = e / CHE, c = (e - s * CHE) * 8;
      const int di = s / HJ - 1, dj = s % HJ - 1;
      const int n = nbase + ((i0 + di) & (NX - 1)) * NX + ((j0 + dj) & (NX - 1));
      *(uint4*)&rawE[s][c] = *(const uint4*)(srcE + ((size_t)n * NB + b) * ssE + soE + c);
    }
  }
  __syncthreads();

  // ---- phase 2: meanA[r] (halo-1 rows) from rawA neighbors ----
  for (int e = tid; e < NH * CHA; e += 256) {
    const int r = e / CHA, c = (e - r * CHA) * 8;
    const int sA = (r / HJ + 1) * RAJ + (r % HJ) + 1;
    *(short8*)&sh.a.meanA[r][c] =
        mean4(&sh.a.rawA[sA - RAJ][c], &sh.a.rawA[sA + RAJ][c],
              &sh.a.rawA[sA - 1][c],   &sh.a.rawA[sA + 1][c]);
  }
  __syncthreads();

  const int lane = tid & 63, wave = tid >> 6;
  const int fn = lane & 15, fg = lane >> 4;

  // ---- phase 3: stage A (swapped MFMA: lane fn = H row, fg*4+j = out col) ----
  {
    const unsigned short* wt = g_wt + wtaOff;
    const int cw = wave % NCWA, rw = wave / NCWA;
    short8 wfA[KSA][CFWA];
    float4 btA[CFWA];
    #pragma unroll
    for (int ks = 0; ks < KSA; ++ks)
      #pragma unroll
      for (int cfl = 0; cfl < CFWA; ++cfl) {
        const int cfg = cw * CFWA + cfl;
        wfA[ks][cfl] = *(const short8*)(wt + (size_t)(cfg * 16 + fn) * KA + ks * 32 + fg * 8);
      }
    #pragma unroll
    for (int cfl = 0; cfl < CFWA; ++cfl)
      btA[cfl] = *(const float4*)(ba + (cw * CFWA + cfl) * 16 + fg * 4);

    #pragma unroll
    for (int rf = rw; rf < 7; rf += RWGA) {
      const int r = rf * 16 + fn;
      const int rc = r < NH ? r : NH - 1;
      const int sA = (rc / HJ + 1) * RAJ + (rc % HJ) + 1;
      f32x4 acc[CFWA];
      #pragma unroll
      for (int cfl = 0; cfl < CFWA; ++cfl)
        acc[cfl] = (f32x4){btA[cfl].x, btA[cfl].y, btA[cfl].z, btA[cfl].w};
      #pragma unroll
      for (int ks = 0; ks < KSA; ++ks) {
        const short8 xf = (ks < FA / 32)
            ? *(const short8*)&sh.a.rawA[sA][ks * 32 + fg * 8]
            : *(const short8*)&sh.a.meanA[rc][(ks - FA / 32) * 32 + fg * 8];
        #pragma unroll
        for (int cfl = 0; cfl < CFWA; ++cfl)
          acc[cfl] = __builtin_amdgcn_mfma_f32_16x16x32_bf16(wfA[ks][cfl], xf, acc[cfl], 0, 0, 0);
      }
      #pragma unroll
      for (int cfl = 0; cfl < CFWA; ++cfl) {
        const int cfg = cw * CFWA + cfl;
        const uint2 u2 = make_uint2(
            cvtpk(fmaxf(acc[cfl][0], 0.f), fmaxf(acc[cfl][1], 0.f)),
            cvtpk(fmaxf(acc[cfl][2], 0.f), fmaxf(acc[cfl][3], 0.f)));
        *(uint2*)&H[r][cfg * 16 + fg * 4] = u2;
      }
    }
  }
  __syncthreads();   // H complete; rawA/meanA dead from here

  // ---- phase 4: meanH (+meanE) for the 64 tile rows, into union region ----
  {
    constexpr int CHH = FOA / 8;
    for (int e = tid; e < 64 * CHH; e += 256) {
      const int r = e / CHH, c = (e - r * CHH) * 8;
      const int sH = (r / TJ + 1) * HJ + (r % TJ) + 1;
      *(short8*)&sh.b.meanH[r][c] =
          mean4(&H[sH - HJ][c], &H[sH + HJ][c], &H[sH - 1][c], &H[sH + 1][c]);
    }
    if constexpr (FEXT != 0) {
      constexpr int CHE = FEXT / 8;
      for (int e = tid; e < 64 * CHE; e += 256) {
        const int r = e / CHE, c = (e - r * CHE) * 8;
        const int sH = (r / TJ + 1) * HJ + (r % TJ) + 1;
        *(short8*)&sh.b.meanE[r][c] =
            mean4(&rawE[sH - HJ][c], &rawE[sH + HJ][c], &rawE[sH - 1][c], &rawE[sH + 1][c]);
      }
    }
  }
  __syncthreads();

  // ---- phase 5: stage B (unswapped MFMA; lane fn = input row AND out col) ----
  {
    const unsigned short* wt = g_wt + wtbOff;
    const int cw = wave % NCWB, rw = wave / NCWB;
    short8 wfB[KSB];
    #pragma unroll
    for (int ks = 0; ks < KSB; ++ks)
      wfB[ks] = *(const short8*)(wt + (size_t)(cw * 16 + fn) * KB + ks * 32 + fg * 8);
    const float bt = bb[cw * 16 + fn];

    constexpr int S1 = FOA / 32;          // self-H ksteps
    constexpr int S2 = S1 + FEXT / 32;    // + self-E
    constexpr int S3 = S2 + FOA / 32;     // + mean-H

    #pragma unroll
    for (int rf = rw; rf < 4; rf += RWGB) {
      const int r = rf * 16 + fn;
      const int sH = (r / TJ + 1) * HJ + (r % TJ) + 1;
      f32x4 acc = (f32x4){bt, bt, bt, bt};
      #pragma unroll
      for (int ks = 0; ks < KSB; ++ks) {
        short8 xf;
        if (ks < S1) {
          xf = *(const short8*)&H[sH][ks * 32 + fg * 8];
        } else if (FEXT != 0 && ks < S2) {
          xf = *(const short8*)&rawE[sH][(ks - S1) * 32 + fg * 8];
        } else if (ks < S3) {
          xf = *(const short8*)&sh.b.meanH[r][(ks - S2) * 32 + fg * 8];
        } else {
          xf = *(const short8*)&sh.b.meanE[FEXT ? r : 0][(ks - S3) * 32 + fg * 8];
        }
        acc = __builtin_amdgcn_mfma_f32_16x16x32_bf16(xf, wfB[ks], acc, 0, 0, 0);
      }
      #pragma unroll
      for (int j = 0; j < 4; ++j) {
        const int rr = rf * 16 + fg * 4 + j;
        const int n = nbase + (i0 + (rr / TJ)) * NX + j0 + (rr % TJ);
        float v = acc[j];
        if (RELUB) v = fmaxf(v, 0.f);
        if constexpr (DSTK == 0)
          ((float*)dst)[((size_t)b * NNODES + n) * FOB + cw * 16 + fn] = v;
        else
          ((unsigned short*)dst)[((size_t)n * NB + b) * dstr + dof + cw * 16 + fn] = f2bf(v);
      }
    }
  }
}

// ============ round-7 single-layer kernel (kept for L3) ============
__device__ __forceinline__ void tile_barrier() {
  asm volatile("s_waitcnt lgkmcnt(0)" ::: "memory");
  __builtin_amdgcn_s_barrier();
  asm volatile("" ::: "memory");
}
constexpr int rows_for(int FIN)            { return FIN == 32 ? 64 : 32; }
constexpr int grid_for(int FIN, int SRCK)  { return (FIN == 128 || SRCK == 0) ? 1024 : 1536; }
constexpr int minw_for(int FIN, int SRCK)  { return (FIN == 128 || SRCK == 0) ? 4 : 6; }

template<int FIN, int FOUT, int SRCK, int DSTK, bool RELU>
__global__ __launch_bounds__(256, minw_for(FIN, SRCK))
void sage_mfma(const void* __restrict__ srcp, int sstride, int soff,
               void* __restrict__ dstp, int dstride, int doff,
               const float* __restrict__ Ws, const float* __restrict__ Wn,
               const float* __restrict__ bias, const int* __restrict__ nbr)
{
  constexpr int ROWS = rows_for(FIN);
  constexpr int GRID = grid_for(FIN, SRCK);
  constexpr int NPT = ROWS / 4;
  constexpr int NTILES = (NNODES * NB) / ROWS;
  constexpr int K = 2 * FIN;
  constexpr int KSTEPS = K / 32;
  constexpr int LD = K + 8;
  constexpr int WAVES_N = (FOUT >= 64) ? 4 : 2;
  constexpr int WAVES_M = 4 / WAVES_N;
  constexpr int CF = FOUT / (16 * WAVES_N);
  constexpr int RF = ROWS / (16 * WAVES_M);
  constexpr int CHUNKS = FIN / 8;
  constexpr int ITERS = (ROWS * CHUNKS) / 256;
  constexpr int PF = ITERS;

  __shared__ unsigned short As[2][ROWS][LD];

  const int tid = threadIdx.x;
  const int wave = tid >> 6, lane = tid & 63;
  const int wn = wave % WAVES_N, wm = wave / WAVES_N;
  const int colbase = wn * (FOUT / WAVES_N);
  const int rowbase = wm * (ROWS / WAVES_M);
  const int fn = lane & 15, fg = lane >> 4;

  short8 Bfrag[KSTEPS][CF];
  float bv[CF];
  #pragma unroll
  for (int ks = 0; ks < KSTEPS; ++ks) {
    const float* wb = (ks * 32 < FIN) ? (Ws + (size_t)(ks * 32) * FOUT)
                                      : (Wn + (size_t)(ks * 32 - FIN) * FOUT);
    #pragma unroll
    for (int cf = 0; cf < CF; ++cf) {
      const int col = colbase + cf * 16 + fn;
      short8 f;
      #pragma unroll
      for (int j = 0; j < 8; ++j)
        f[j] = (short)f2bf(wb[(size_t)(fg * 8 + j) * FOUT + col]);
      Bfrag[ks][cf] = f;
    }
  }
  #pragma unroll
  for (int cf = 0; cf < CF; ++cf) bv[cf] = bias[colbase + cf * 16 + fn];

  struct G1 { ushort8 s, n0, n1, n2, n3; };
  using PG = G1;

  auto issue = [&](int node0, int it, PG& p) {
    const int g = tid + it * 256;
    const int r = g / CHUNKS;
    const int c = (g - r * CHUNKS) * 8;
    const int n = node0 + (r >> 2);
    const int b = r & 3;
    const int4 nb4 = reinterpret_cast<const int4*>(nbr)[n];
    const unsigned short* s = (const unsigned short*)srcp;
    auto ld = [&](int nn) {
      return *reinterpret_cast<const ushort8*>(s + ((size_t)nn * NB + b) * sstride + soff + c);
    };
    p.s = ld(n); p.n0 = ld(nb4.x); p.n1 = ld(nb4.y); p.n2 = ld(nb4.z); p.n3 = ld(nb4.w);
  };
  auto finish = [&](int buf, int it, PG& p) {
    const int g = tid + it * 256;
    const int r = g / CHUNKS;
    const int c = (g - r * CHUNKS) * 8;
    uint4 xv = make_uint4(
        (unsigned)(unsigned short)p.s[0] | ((unsigned)(unsigned short)p.s[1] << 16),
        (unsigned)(unsigned short)p.s[2] | ((unsigned)(unsigned short)p.s[3] << 16),
        (unsigned)(unsigned short)p.s[4] | ((unsigned)(unsigned short)p.s[5] << 16),
        (unsigned)(unsigned short)p.s[6] | ((unsigned)(unsigned short)p.s[7] << 16));
    float sum[8];
    #pragma unroll
    for (int j = 0; j < 8; ++j)
      sum[j] = (bf2f(p.n0[j]) + bf2f(p.n1[j])) + (bf2f(p.n2[j]) + bf2f(p.n3[j]));
    uint4 mv = make_uint4(cvtpk(sum[0] * 0.25f, sum[1] * 0.25f), cvtpk(sum[2] * 0.25f, sum[3] * 0.25f),
                          cvtpk(sum[4] * 0.25f, sum[5] * 0.25f), cvtpk(sum[6] * 0.25f, sum[7] * 0.25f));
    *reinterpret_cast<uint4*>(&As[buf][r][c]) = xv;
    *reinterpret_cast<uint4*>(&As[buf][r][FIN + c]) = mv;
  };

  {
    PG p[ITERS];
    #pragma unroll
    for (int it = 0; it < ITERS; ++it) issue(blockIdx.x * NPT, it, p[it]);
    #pragma unroll
    for (int it = 0; it < ITERS; ++it) finish(0, it, p[it]);
  }

  int cur = 0;
  for (int tile = blockIdx.x; tile < NTILES; tile += GRID) {
    const int node0 = tile * NPT;
    const bool hasnext = (tile + GRID) < NTILES;
    const int nnode0 = (tile + GRID) * NPT;

    PG ptop[PF];
    if (hasnext) {
      #pragma unroll
      for (int it = 0; it < PF; ++it) issue(nnode0, it, ptop[it]);
    }

    tile_barrier();

    f32x4 acc[RF][CF];
    #pragma unroll
    for (int rf = 0; rf < RF; ++rf)
      #pragma unroll
      for (int cf = 0; cf < CF; ++cf)
        acc[rf][cf] = (f32x4){bv[cf], bv[cf], bv[cf], bv[cf]};

    #pragma unroll
    for (int ks = 0; ks < KSTEPS; ++ks) {
      short8 a[RF];
      #pragma unroll
      for (int rf = 0; rf < RF; ++rf)
        a[rf] = *reinterpret_cast<const short8*>(&As[cur][rowbase + rf * 16 + fn][ks * 32 + fg * 8]);
      #pragma unroll
      for (int rf = 0; rf < RF; ++rf)
        #pragma unroll
        for (int cf = 0; cf < CF; ++cf)
          acc[rf][cf] = __builtin_amdgcn_mfma_f32_16x16x32_bf16(
              a[rf], Bfrag[ks][cf], acc[rf][cf], 0, 0, 0);
    }

    #pragma unroll
    for (int rf = 0; rf < RF; ++rf) {
      #pragma unroll
      for (int cf = 0; cf < CF; ++cf) {
        const int col = colbase + cf * 16 + fn;
        #pragma unroll
        for (int j = 0; j < 4; ++j) {
          const int row = rowbase + rf * 16 + fg * 4 + j;
          const int n = node0 + (row >> 2);
          const int b = row & 3;
          float v = acc[rf][cf][j];
          if (RELU) v = fmaxf(v, 0.f);
          if (DSTK == 0)
            ((float*)dstp)[((size_t)b * NNODES + n) * FOUT + col] = v;
          else
            ((unsigned short*)dstp)[((size_t)n * NB + b) * dstride + doff + col] = f2bf(v);
        }
      }
    }

    if (hasnext) {
      #pragma unroll
      for (int it = 0; it < PF; ++it) finish(cur ^ 1, it, ptop[it]);
    }
    cur ^= 1;
  }
}

extern "C" void kernel_launch(void* const* d_in, const int* in_sizes, int n_in,
                              void* d_out, int out_size, void* d_ws, size_t ws_size,
                              hipStream_t stream) {
  const float* x  = (const float*)d_in[0];   // [B, N, 64] fp32
  const int* nbr  = (const int*)d_in[1];     // [N, 4] int32
  const float* W1s = (const float*)d_in[2],  *W1n = (const float*)d_in[3],  *b1 = (const float*)d_in[4];
  const float* W2s = (const float*)d_in[5],  *W2n = (const float*)d_in[6],  *b2 = (const float*)d_in[7];
  const float* W3s = (const float*)d_in[8],  *W3n = (const float*)d_in[9],  *b3 = (const float*)d_in[10];
  const float* W4s = (const float*)d_in[11], *W4n = (const float*)d_in[12], *b4 = (const float*)d_in[13];
  const float* W5s = (const float*)d_in[14], *W5n = (const float*)d_in[15], *b5 = (const float*)d_in[16];
  const float* W6s = (const float*)d_in[17], *W6n = (const float*)d_in[18], *b6 = (const float*)d_in[19];

  // hbuf [N,4,128] bf16: cols 0:32 = h5a, 32:64 = h3, 64:128 = h2.
  // h1, h4, h6a never hit HBM (fused). d_out is pure output.
  unsigned short* hbuf = (unsigned short*)d_ws;

  const dim3 blk(256);

  prep_wt<<<dim3(32), blk, 0, stream>>>(W1s, W1n, 64, 128, WT_A12);
  prep_wt<<<dim3(32), blk, 0, stream>>>(W2s, W2n, 128, 64, WT_B12);
  prep_wt<<<dim3(8),  blk, 0, stream>>>(W4s, W4n, 32, 32, WT_45);
  prep_wt<<<dim3(16), blk, 0, stream>>>(W5s, W5n, 64, 64, WT_A67);
  prep_wt<<<dim3(32), blk, 0, stream>>>(W6s, W6n, 128, 64, WT_B67);

  // L1+L2 fused: x (fp32) -> h2 (cols 64:128)
  sage_fused2<64, 128, 0, 64, 0, 1, true, 2><<<dim3(6144), blk, 0, stream>>>(
      x, 0, 0, nullptr, 0, 0, hbuf, 128, 64, WT_A12, WT_B12, b1, b2);
  // L3 (unfused, proven): h2 -> h3 (cols 32:64)
  sage_mfma<64, 32, 1, 1, true><<<dim3(grid_for(64, 1)), blk, 0, stream>>>(
      hbuf, 128, 64, hbuf, 128, 32, W3s, W3n, b3, nbr);
  // L4+L5 fused (shared W4): h3 -> h5a (cols 0:32)
  sage_fused2<32, 32, 0, 32, 1, 1, true, 4><<<dim3(6144), blk, 0, stream>>>(
      hbuf, 128, 32, nullptr, 0, 0, hbuf, 128, 0, WT_45, WT_45, b4, b4);
  // L6+L7 fused: [h5a|h3] (cols 0:64) + ext h2 (cols 64:128) -> out fp32
  sage_fused2<64, 64, 64, 64, 1, 0, false, 2><<<dim3(6144), blk, 0, stream>>>(
      hbuf, 128, 0, hbuf, 128, 64, d_out, 0, 0, WT_A67, WT_B67, b5, b6);
}

// Round 11
// 220.047 us; speedup vs baseline: 2.5146x; 1.4244x over previous
//
#include <hip/hip_runtime.h>
#include <type_traits>

#define NNODES 98304
#define NB 4
#define NX 128
#define FACE (NX * NX)

typedef __attribute__((ext_vector_type(8))) short short8;
typedef __attribute__((ext_vector_type(8))) unsigned short ushort8;
typedef __attribute__((ext_vector_type(4))) float f32x4;

__device__ __forceinline__ float bf2f(unsigned short u) {
  union { unsigned int u; float f; } c; c.u = ((unsigned int)u) << 16; return c.f;
}
__device__ __forceinline__ unsigned short f2bf(float f) {
  union { float f; unsigned int u; } c; c.f = f;
  unsigned int r = 0x7FFFu + ((c.u >> 16) & 1u);
  return (unsigned short)((c.u + r) >> 16);
}
// packed f32x2 -> bf16x2 (RNE); low16 = lo
__device__ __forceinline__ unsigned int cvtpk(float lo, float hi) {
  unsigned int r;
  asm("v_cvt_pk_bf16_f32 %0, %1, %2" : "=v"(r) : "v"(lo), "v"(hi));
  return r;
}

// Analytic 4-neighborhood on the per-face periodic NX x NX grid.
// Matches reference _build_neighbors: up(i-1), down(i+1), left(j-1), right(j+1),
// all mod NX within the face. ~12 ALU ops -- removes the nbr-table load that
// serialized a full memory round-trip in front of every gather.
__device__ __forceinline__ int4 nbr4(int n) {
  const int base = n & ~(FACE - 1);
  const int i = (n >> 7) & (NX - 1);
  const int j = n & (NX - 1);
  const int iu = (i + NX - 1) & (NX - 1), id = (i + 1) & (NX - 1);
  const int jl = (j + NX - 1) & (NX - 1), jr = (j + 1) & (NX - 1);
  return make_int4(base + (iu << 7) + j, base + (id << 7) + j,
                   base + (i << 7) + jl, base + (i << 7) + jr);
}

// Raw tile barrier: drains ONLY LDS (lgkmcnt), NOT vmcnt -- prefetch global
// loads stay in flight across the barrier.
__device__ __forceinline__ void tile_barrier() {
  asm volatile("s_waitcnt lgkmcnt(0)" ::: "memory");
  __builtin_amdgcn_s_barrier();
  asm volatile("" ::: "memory");
}

// Tile geometry / residency policy.
constexpr int rows_for(int FIN)            { return FIN == 32 ? 64 : 32; }
constexpr int grid_for(int FIN, int SRCK)  { return (FIN == 128 || SRCK == 0) ? 1024 : 1536; }
constexpr int minw_for(int FIN, int SRCK)  { return (FIN == 128 || SRCK == 0) ? 4 : 6; }

// Fused SAGE layer via MFMA: out = relu?( [X | mean4(X)] @ [Ws; Wn] + b ).
// Double-buffered LDS, ONE lgkm-only barrier per tile, next-tile gather
// issued before the barrier (analytic neighbors -> single-latency chain).
// SRCK: 0 = fp32 [B, N, FIN]; 1 = bf16 [N, B, sstride] + col offset soff.
// DSTK: 0 = fp32 [B, N, FOUT]; 1 = bf16 [N, B, dstride] + doff.
template<int FIN, int FOUT, int SRCK, int DSTK, bool RELU>
__global__ __launch_bounds__(256, minw_for(FIN, SRCK))
void sage_mfma(const void* __restrict__ srcp, int sstride, int soff,
               void* __restrict__ dstp, int dstride, int doff,
               const float* __restrict__ Ws, const float* __restrict__ Wn,
               const float* __restrict__ bias)
{
  constexpr int ROWS = rows_for(FIN);
  constexpr int GRID = grid_for(FIN, SRCK);
  constexpr int NPT = ROWS / 4;                  // nodes per tile
  constexpr int NTILES = (NNODES * NB) / ROWS;
  constexpr int K = 2 * FIN;                     // fused K: self | mean
  constexpr int KSTEPS = K / 32;
  constexpr int LD = K + 8;                      // +16B pad (2-way conflict, free)
  constexpr int WAVES_N = (FOUT >= 64) ? 4 : 2;
  constexpr int WAVES_M = 4 / WAVES_N;
  constexpr int CF = FOUT / (16 * WAVES_N);      // col frags per wave
  constexpr int RF = ROWS / (16 * WAVES_M);      // row frags per wave
  constexpr int CHUNKS = FIN / 8;
  constexpr int ITERS = (ROWS * CHUNKS) / 256;   // staging groups per thread (1 or 2)
  constexpr int PF = ITERS;

  __shared__ unsigned short As[2][ROWS][LD];

  const int tid = threadIdx.x;
  const int wave = tid >> 6, lane = tid & 63;
  const int wn = wave % WAVES_N, wm = wave / WAVES_N;
  const int colbase = wn * (FOUT / WAVES_N);
  const int rowbase = wm * (ROWS / WAVES_M);
  const int fn = lane & 15, fg = lane >> 4;

  // ---- weight fragments (B-operand = [Ws;Wn]), built once per block ----
  short8 Bfrag[KSTEPS][CF];
  float bv[CF];
  #pragma unroll
  for (int ks = 0; ks < KSTEPS; ++ks) {
    const float* wb = (ks * 32 < FIN) ? (Ws + (size_t)(ks * 32) * FOUT)
                                      : (Wn + (size_t)(ks * 32 - FIN) * FOUT);
    #pragma unroll
    for (int cf = 0; cf < CF; ++cf) {
      const int col = colbase + cf * 16 + fn;
      short8 f;
      #pragma unroll
      for (int j = 0; j < 8; ++j)
        f[j] = (short)f2bf(wb[(size_t)(fg * 8 + j) * FOUT + col]);
      Bfrag[ks][cf] = f;
    }
  }
  #pragma unroll
  for (int cf = 0; cf < CF; ++cf) bv[cf] = bias[colbase + cf * 16 + fn];

  struct G0 { float4 s0, s1, a0, a1, b0, b1, c0, c1, d0, d1; };
  struct G1 { ushort8 s, n0, n1, n2, n3; };
  using PG = typename std::conditional<SRCK == 0, G0, G1>::type;

  // issue: analytic neighbors + fire global loads (no nbr-table round trip)
  auto issue = [&](int node0, int it, PG& p) {
    const int g = tid + it * 256;
    const int r = g / CHUNKS;
    const int c = (g - r * CHUNKS) * 8;
    const int n = node0 + (r >> 2);
    const int b = r & 3;
    const int4 nb4 = nbr4(n);
    if constexpr (SRCK == 0) {
      const float* s = (const float*)srcp;
      const float* ps = s + ((size_t)b * NNODES + n) * FIN + c;
      const float* p0 = s + ((size_t)b * NNODES + nb4.x) * FIN + c;
      const float* p1 = s + ((size_t)b * NNODES + nb4.y) * FIN + c;
      const float* p2 = s + ((size_t)b * NNODES + nb4.z) * FIN + c;
      const float* p3 = s + ((size_t)b * NNODES + nb4.w) * FIN + c;
      p.s0 = *(const float4*)ps; p.s1 = *(const float4*)(ps + 4);
      p.a0 = *(const float4*)p0; p.a1 = *(const float4*)(p0 + 4);
      p.b0 = *(const float4*)p1; p.b1 = *(const float4*)(p1 + 4);
      p.c0 = *(const float4*)p2; p.c1 = *(const float4*)(p2 + 4);
      p.d0 = *(const float4*)p3; p.d1 = *(const float4*)(p3 + 4);
    } else {
      const unsigned short* s = (const unsigned short*)srcp;
      auto ld = [&](int nn) {
        return *reinterpret_cast<const ushort8*>(s + ((size_t)nn * NB + b) * sstride + soff + c);
      };
      p.s = ld(n); p.n0 = ld(nb4.x); p.n1 = ld(nb4.y); p.n2 = ld(nb4.z); p.n3 = ld(nb4.w);
    }
  };

  // finish: convert + mean + LDS write into buffer `buf`
  auto finish = [&](int buf, int it, PG& p) {
    const int g = tid + it * 256;
    const int r = g / CHUNKS;
    const int c = (g - r * CHUNKS) * 8;
    uint4 xv, mv;
    if constexpr (SRCK == 0) {
      xv = make_uint4(cvtpk(p.s0.x, p.s0.y), cvtpk(p.s0.z, p.s0.w),
                      cvtpk(p.s1.x, p.s1.y), cvtpk(p.s1.z, p.s1.w));
      float4 m0, m1;
      m0.x = (p.a0.x + p.b0.x) + (p.c0.x + p.d0.x);
      m0.y = (p.a0.y + p.b0.y) + (p.c0.y + p.d0.y);
      m0.z = (p.a0.z + p.b0.z) + (p.c0.z + p.d0.z);
      m0.w = (p.a0.w + p.b0.w) + (p.c0.w + p.d0.w);
      m1.x = (p.a1.x + p.b1.x) + (p.c1.x + p.d1.x);
      m1.y = (p.a1.y + p.b1.y) + (p.c1.y + p.d1.y);
      m1.z = (p.a1.z + p.b1.z) + (p.c1.z + p.d1.z);
      m1.w = (p.a1.w + p.b1.w) + (p.c1.w + p.d1.w);
      mv = make_uint4(cvtpk(m0.x * 0.25f, m0.y * 0.25f), cvtpk(m0.z * 0.25f, m0.w * 0.25f),
                      cvtpk(m1.x * 0.25f, m1.y * 0.25f), cvtpk(m1.z * 0.25f, m1.w * 0.25f));
    } else {
      union { ushort8 s; uint4 u; } pun;       // bit-identical repack, 0 VALU
      pun.s = p.s;
      xv = pun.u;
      float sum[8];
      #pragma unroll
      for (int j = 0; j < 8; ++j)
        sum[j] = (bf2f(p.n0[j]) + bf2f(p.n1[j])) + (bf2f(p.n2[j]) + bf2f(p.n3[j]));
      mv = make_uint4(cvtpk(sum[0] * 0.25f, sum[1] * 0.25f), cvtpk(sum[2] * 0.25f, sum[3] * 0.25f),
                      cvtpk(sum[4] * 0.25f, sum[5] * 0.25f), cvtpk(sum[6] * 0.25f, sum[7] * 0.25f));
    }
    *reinterpret_cast<uint4*>(&As[buf][r][c]) = xv;
    *reinterpret_cast<uint4*>(&As[buf][r][FIN + c]) = mv;
  };

  // ---- prologue: stage first tile into buf 0 ----
  {
    PG p[ITERS];
    #pragma unroll
    for (int it = 0; it < ITERS; ++it) issue(blockIdx.x * NPT, it, p[it]);
    #pragma unroll
    for (int it = 0; it < ITERS; ++it) finish(0, it, p[it]);
  }

  // ---- main loop: one lgkm-only barrier per tile ----
  int cur = 0;
  for (int tile = blockIdx.x; tile < NTILES; tile += GRID) {
    const int node0 = tile * NPT;
    const bool hasnext = (tile + GRID) < NTILES;
    const int nnode0 = (tile + GRID) * NPT;

    PG ptop[PF];
    if (hasnext) {
      #pragma unroll
      for (int it = 0; it < PF; ++it) issue(nnode0, it, ptop[it]);
    }

    tile_barrier();   // buf[cur] ds_writes visible; prefetch loads UNAFFECTED

    f32x4 acc[RF][CF];
    #pragma unroll
    for (int rf = 0; rf < RF; ++rf)
      #pragma unroll
      for (int cf = 0; cf < CF; ++cf)
        acc[rf][cf] = (f32x4){bv[cf], bv[cf], bv[cf], bv[cf]};

    #pragma unroll
    for (int ks = 0; ks < KSTEPS; ++ks) {
      short8 a[RF];
      #pragma unroll
      for (int rf = 0; rf < RF; ++rf)
        a[rf] = *reinterpret_cast<const short8*>(&As[cur][rowbase + rf * 16 + fn][ks * 32 + fg * 8]);
      #pragma unroll
      for (int rf = 0; rf < RF; ++rf)
        #pragma unroll
        for (int cf = 0; cf < CF; ++cf)
          acc[rf][cf] = __builtin_amdgcn_mfma_f32_16x16x32_bf16(
              a[rf], Bfrag[ks][cf], acc[rf][cf], 0, 0, 0);
    }

    // ---- store (C/D map: col = lane&15, row = (lane>>4)*4 + j) ----
    #pragma unroll
    for (int rf = 0; rf < RF; ++rf) {
      #pragma unroll
      for (int cf = 0; cf < CF; ++cf) {
        const int col = colbase + cf * 16 + fn;
        #pragma unroll
        for (int j = 0; j < 4; ++j) {
          const int row = rowbase + rf * 16 + fg * 4 + j;
          const int n = node0 + (row >> 2);
          const int b = row & 3;
          float v = acc[rf][cf][j];
          if (RELU) v = fmaxf(v, 0.f);
          if (DSTK == 0)
            ((float*)dstp)[((size_t)b * NNODES + n) * FOUT + col] = v;
          else
            ((unsigned short*)dstp)[((size_t)n * NB + b) * dstride + doff + col] = f2bf(v);
        }
      }
    }

    // ---- stage next tile into the other buffer (no extra barrier) ----
    if (hasnext) {
      #pragma unroll
      for (int it = 0; it < PF; ++it) finish(cur ^ 1, it, ptop[it]);
    }
    cur ^= 1;
  }
}

extern "C" void kernel_launch(void* const* d_in, const int* in_sizes, int n_in,
                              void* d_out, int out_size, void* d_ws, size_t ws_size,
                              hipStream_t stream) {
  const float* x  = (const float*)d_in[0];   // [B, N, 64] fp32
  const float* W1s = (const float*)d_in[2],  *W1n = (const float*)d_in[3],  *b1 = (const float*)d_in[4];
  const float* W2s = (const float*)d_in[5],  *W2n = (const float*)d_in[6],  *b2 = (const float*)d_in[7];
  const float* W3s = (const float*)d_in[8],  *W3n = (const float*)d_in[9],  *b3 = (const float*)d_in[10];
  const float* W4s = (const float*)d_in[11], *W4n = (const float*)d_in[12], *b4 = (const float*)d_in[13];
  const float* W5s = (const float*)d_in[14], *W5n = (const float*)d_in[15], *b5 = (const float*)d_in[16];
  const float* W6s = (const float*)d_in[17], *W6n = (const float*)d_in[18], *b6 = (const float*)d_in[19];

  // Buffers (bf16 intermediates):
  //   h1   [N,B,128] bf16  -> d_out (exactly out bytes), dead after L2
  //   h6buf[N,B,128] bf16  -> d_ws   (h2 in cols 64:128, sage6-out in cols 0:64)
  //   h5buf[N,B, 64] bf16  -> d_out  (h3 in cols 32:64, sage5-out in cols 0:32)
  //   h4   [N,B, 32] bf16  -> d_out + 50.33MB
  unsigned short* h1 = (unsigned short*)d_out;
  unsigned short* h6 = (unsigned short*)d_ws;
  unsigned short* h5 = (unsigned short*)d_out;
  unsigned short* h4 = (unsigned short*)((char*)d_out + (size_t)NNODES * NB * 64 * 2);

  const dim3 block(256);

  // L1: x(fp32) -> h1 [*,128]
  sage_mfma<64, 128, 0, 1, true><<<dim3(grid_for(64, 0)), block, 0, stream>>>(x, 0, 0, h1, 128, 0, W1s, W1n, b1);
  // L2: h1 -> h2 = h6buf cols 64:128
  sage_mfma<128, 64, 1, 1, true><<<dim3(grid_for(128, 1)), block, 0, stream>>>(h1, 128, 0, h6, 128, 64, W2s, W2n, b2);
  // L3: h2 -> h3 = h5buf cols 32:64
  sage_mfma<64, 32, 1, 1, true><<<dim3(grid_for(64, 1)), block, 0, stream>>>(h6, 128, 64, h5, 64, 32, W3s, W3n, b3);
  // L4: h3 -> h4
  sage_mfma<32, 32, 1, 1, true><<<dim3(grid_for(32, 1)), block, 0, stream>>>(h5, 64, 32, h4, 32, 0, W4s, W4n, b4);
  // L5: h4 -> h5buf cols 0:32 (layer-4 weights reused, per reference)
  sage_mfma<32, 32, 1, 1, true><<<dim3(grid_for(32, 1)), block, 0, stream>>>(h4, 32, 0, h5, 64, 0, W4s, W4n, b4);
  // L6: h5 -> h6buf cols 0:64
  sage_mfma<64, 64, 1, 1, true><<<dim3(grid_for(64, 1)), block, 0, stream>>>(h5, 64, 0, h6, 128, 0, W5s, W5n, b5);
  // L7: h6 -> out fp32 [B,N,64], no relu
  sage_mfma<128, 64, 1, 0, false><<<dim3(grid_for(128, 1)), block, 0, stream>>>(h6, 128, 0, d_out, 0, 0, W6s, W6n, b6);
}